// Round 1
// baseline (85.107 us; speedup 1.0000x reference)
//
#include <hip/hip_runtime.h>

#define N_ 8
#define C_ 64
#define P_ 4096
#define TILE 128

typedef float f32x4 __attribute__((ext_vector_type(4)));
typedef short bf16x8 __attribute__((ext_vector_type(8)));

__device__ __forceinline__ unsigned short f2bf(float f) {
  unsigned int u = __builtin_bit_cast(unsigned int, f);
  u = (u + 0x7fffu + ((u >> 16) & 1u)) >> 16;  // RNE
  return (unsigned short)u;
}

// Kernel 1: L2-normalize along C (stride-P reads, coalesced across lanes),
// write bf16 transposed to [N][P][C] so GEMM fragment loads are contiguous.
__global__ void __launch_bounds__(256) norm_transpose(
    const float* __restrict__ rgb, const float* __restrict__ ir,
    unsigned short* __restrict__ rgbnT, unsigned short* __restrict__ irnT) {
  const int idx = blockIdx.x * 256 + threadIdx.x;  // over N*P
  const int n = idx >> 12;
  const int p = idx & (P_ - 1);
  const float* src = (blockIdx.y == 0) ? rgb : ir;
  unsigned short* dst = (blockIdx.y == 0) ? rgbnT : irnT;
  const float* col = src + (size_t)n * C_ * P_ + p;
  float v[C_];
  float ss = 0.f;
#pragma unroll
  for (int c = 0; c < C_; ++c) {
    v[c] = col[(size_t)c * P_];
    ss += v[c] * v[c];
  }
  const float inv = 1.0f / fmaxf(sqrtf(ss), 1e-12f);
  unsigned short* o = dst + ((size_t)n * P_ + p) * C_;
#pragma unroll
  for (int g = 0; g < 8; ++g) {
    bf16x8 pack;
#pragma unroll
    for (int j = 0; j < 8; ++j) pack[j] = (short)f2bf(v[g * 8 + j] * inv);
    *reinterpret_cast<bf16x8*>(o + g * 8) = pack;
  }
}

// Kernel 2: per-n GEMM sim = rgbnT^T(?) -> sim[p][q] = sum_c A[p][c]*B[q][c],
// fused exp(sim/T) + per-block {diag, total} partial reduction.
// 128x128 tile per block, 4 waves in 2x2, each wave 64x64 via 4x4 MFMA frags.
__global__ void __launch_bounds__(256) gemm_exp_reduce(
    const unsigned short* __restrict__ aT, const unsigned short* __restrict__ bT,
    float* __restrict__ partials) {
  const int n = blockIdx.z;
  const int p0 = blockIdx.x * TILE;
  const int q0 = blockIdx.y * TILE;
  const int lane = threadIdx.x & 63;
  const int wid = threadIdx.x >> 6;
  const int wr = wid >> 1, wc = wid & 1;
  const int pbase = p0 + wr * 64;
  const int qbase = q0 + wc * 64;
  const unsigned short* A = aT + (size_t)n * P_ * C_;  // [P][C]
  const unsigned short* B = bT + (size_t)n * P_ * C_;  // [P][C]
  const int r16 = lane & 15;
  const int kofs = (lane >> 4) * 8;

  f32x4 acc[4][4];
#pragma unroll
  for (int i = 0; i < 4; ++i)
#pragma unroll
    for (int j = 0; j < 4; ++j) acc[i][j] = (f32x4)(0.f);

#pragma unroll
  for (int ks = 0; ks < 2; ++ks) {
    const int k0 = ks * 32 + kofs;
    bf16x8 a[4], b[4];
#pragma unroll
    for (int i = 0; i < 4; ++i)
      a[i] = *reinterpret_cast<const bf16x8*>(
          A + (size_t)(pbase + i * 16 + r16) * C_ + k0);
#pragma unroll
    for (int i = 0; i < 4; ++i)
      b[i] = *reinterpret_cast<const bf16x8*>(
          B + (size_t)(qbase + i * 16 + r16) * C_ + k0);
#pragma unroll
    for (int mi = 0; mi < 4; ++mi)
#pragma unroll
      for (int ni = 0; ni < 4; ++ni)
        acc[mi][ni] = __builtin_amdgcn_mfma_f32_16x16x32_bf16(
            a[mi], b[ni], acc[mi][ni], 0, 0, 0);
  }

  // Epilogue: logit = exp(sim/0.1) = exp2(sim * 10 * log2(e))
  const float SC = 14.4269504088896340736f;
  float tot = 0.f, pos = 0.f;
  const int col = lane & 15;
  const int rowb = (lane >> 4) * 4;
#pragma unroll
  for (int mi = 0; mi < 4; ++mi) {
#pragma unroll
    for (int ni = 0; ni < 4; ++ni) {
#pragma unroll
      for (int r = 0; r < 4; ++r) {
        float e = __builtin_amdgcn_exp2f(acc[mi][ni][r] * SC);
        tot += e;
        const int gp = pbase + mi * 16 + rowb + r;
        const int gq = qbase + ni * 16 + col;
        pos += (gp == gq) ? e : 0.f;
      }
    }
  }
  // wave reduce (64 lanes)
#pragma unroll
  for (int off = 32; off > 0; off >>= 1) {
    tot += __shfl_down(tot, off);
    pos += __shfl_down(pos, off);
  }
  __shared__ float sb[8];
  if (lane == 0) { sb[wid * 2] = pos; sb[wid * 2 + 1] = tot; }
  __syncthreads();
  if (threadIdx.x == 0) {
    const float pp = sb[0] + sb[2] + sb[4] + sb[6];
    const float tt = sb[1] + sb[3] + sb[5] + sb[7];
    const int bid = (n * 32 + blockIdx.y) * 32 + blockIdx.x;
    partials[bid * 2] = pp;
    partials[bid * 2 + 1] = tt;
  }
}

// Kernel 3: deterministic final reduction (1024 partials per n) + loss.
__global__ void __launch_bounds__(1024) finalize(
    const float* __restrict__ partials, float* __restrict__ out) {
  const int tid = threadIdx.x;
  const int lane = tid & 63, wid = tid >> 6;
  __shared__ float sp[16], st[16];
  float loss = 0.f;
  for (int n = 0; n < N_; ++n) {
    float p = partials[(n * 1024 + tid) * 2];
    float t = partials[(n * 1024 + tid) * 2 + 1];
#pragma unroll
    for (int off = 32; off > 0; off >>= 1) {
      p += __shfl_down(p, off);
      t += __shfl_down(t, off);
    }
    if (lane == 0) { sp[wid] = p; st[wid] = t; }
    __syncthreads();
    if (tid == 0) {
      float pp = 0.f, tt = 0.f;
#pragma unroll
      for (int w = 0; w < 16; ++w) { pp += sp[w]; tt += st[w]; }
      loss += -logf(pp / (tt + 1e-6f));
    }
    __syncthreads();
  }
  if (tid == 0) out[0] = loss * (1.0f / N_);
}

extern "C" void kernel_launch(void* const* d_in, const int* in_sizes, int n_in,
                              void* d_out, int out_size, void* d_ws, size_t ws_size,
                              hipStream_t stream) {
  const float* rgb = (const float*)d_in[0];
  const float* ir = (const float*)d_in[1];
  float* out = (float*)d_out;

  unsigned short* rgbnT = (unsigned short*)d_ws;              // 4 MB
  unsigned short* irnT = rgbnT + (size_t)N_ * P_ * C_;        // 4 MB
  float* partials = (float*)(irnT + (size_t)N_ * P_ * C_);    // 64 KB

  dim3 g1(N_ * P_ / 256, 2);
  norm_transpose<<<g1, 256, 0, stream>>>(rgb, ir, rgbnT, irnT);

  dim3 g2(P_ / TILE, P_ / TILE, N_);
  gemm_exp_reduce<<<g2, 256, 0, stream>>>(rgbnT, irnT, partials);

  finalize<<<1, 1024, 0, stream>>>(partials, out);
}

// Round 2
// 84.535 us; speedup vs baseline: 1.0068x; 1.0068x over previous
//
#include <hip/hip_runtime.h>

#define N_ 8
#define C_ 64
#define P_ 4096
#define TILE 128

typedef float f32x4 __attribute__((ext_vector_type(4)));
typedef short bf16x8 __attribute__((ext_vector_type(8)));

__device__ __forceinline__ unsigned short f2bf(float f) {
  unsigned int u = __builtin_bit_cast(unsigned int, f);
  u = (u + 0x7fffu + ((u >> 16) & 1u)) >> 16;  // RNE
  return (unsigned short)u;
}

// Kernel 1: L2-normalize along C, write bf16 transposed to [N][P][C].
// rgb side is pre-scaled by 10*log2(e) so the GEMM epilogue is exp2(acc).
__global__ void __launch_bounds__(256) norm_transpose(
    const float* __restrict__ rgb, const float* __restrict__ ir,
    unsigned short* __restrict__ rgbnT, unsigned short* __restrict__ irnT) {
  const int idx = blockIdx.x * 256 + threadIdx.x;  // over N*P
  const int n = idx >> 12;
  const int p = idx & (P_ - 1);
  const float* src = (blockIdx.y == 0) ? rgb : ir;
  unsigned short* dst = (blockIdx.y == 0) ? rgbnT : irnT;
  const float SC = 14.4269504088896340736f;  // 10*log2(e)
  const float* col = src + (size_t)n * C_ * P_ + p;
  float v[C_];
  float ss = 0.f;
#pragma unroll
  for (int c = 0; c < C_; ++c) {
    v[c] = col[(size_t)c * P_];
    ss += v[c] * v[c];
  }
  float inv = 1.0f / fmaxf(sqrtf(ss), 1e-12f);
  if (blockIdx.y == 0) inv *= SC;
  unsigned short* o = dst + ((size_t)n * P_ + p) * C_;
#pragma unroll
  for (int g = 0; g < 8; ++g) {
    bf16x8 pack;
#pragma unroll
    for (int j = 0; j < 8; ++j) pack[j] = (short)f2bf(v[g * 8 + j] * inv);
    *reinterpret_cast<bf16x8*>(o + g * 8) = pack;
  }
}

// Kernel 2: sim[p][q] = sum_c A[p][c]*B[q][c] (A pre-scaled by 10*log2e),
// fused exp2 + per-block {diag, total} partial reduction.
// 128x128 tile per block, 4 waves 2x2, each wave 64x64 via 4x4 MFMA frags.
__global__ void __launch_bounds__(256) gemm_exp_reduce(
    const unsigned short* __restrict__ aT, const unsigned short* __restrict__ bT,
    float* __restrict__ partials) {
  const int n = blockIdx.z;
  const int p0 = blockIdx.x * TILE;
  const int q0 = blockIdx.y * TILE;
  const int lane = threadIdx.x & 63;
  const int wid = threadIdx.x >> 6;
  const int wr = wid >> 1, wc = wid & 1;
  const int pbase = p0 + wr * 64;
  const int qbase = q0 + wc * 64;
  const unsigned short* A = aT + (size_t)n * P_ * C_;  // [P][C]
  const unsigned short* B = bT + (size_t)n * P_ * C_;  // [P][C]
  const int r16 = lane & 15;
  const int kofs = (lane >> 4) * 8;

  f32x4 acc[4][4];
#pragma unroll
  for (int i = 0; i < 4; ++i)
#pragma unroll
    for (int j = 0; j < 4; ++j) acc[i][j] = (f32x4)(0.f);

#pragma unroll
  for (int ks = 0; ks < 2; ++ks) {
    const int k0 = ks * 32 + kofs;
    bf16x8 a[4], b[4];
#pragma unroll
    for (int i = 0; i < 4; ++i)
      a[i] = *reinterpret_cast<const bf16x8*>(
          A + (size_t)(pbase + i * 16 + r16) * C_ + k0);
#pragma unroll
    for (int i = 0; i < 4; ++i)
      b[i] = *reinterpret_cast<const bf16x8*>(
          B + (size_t)(qbase + i * 16 + r16) * C_ + k0);
#pragma unroll
    for (int mi = 0; mi < 4; ++mi)
#pragma unroll
      for (int ni = 0; ni < 4; ++ni)
        acc[mi][ni] = __builtin_amdgcn_mfma_f32_16x16x32_bf16(
            a[mi], b[ni], acc[mi][ni], 0, 0, 0);
  }

  // Epilogue: logit = exp2(acc) (temperature scale folded into A).
  // 4 independent accumulators break the dependent-add chain.
  float t0 = 0.f, t1 = 0.f, t2 = 0.f, t3 = 0.f;
#pragma unroll
  for (int mi = 0; mi < 4; ++mi)
#pragma unroll
    for (int ni = 0; ni < 4; ++ni) {
      const f32x4 v = acc[mi][ni];
      t0 += __builtin_amdgcn_exp2f(v[0]);
      t1 += __builtin_amdgcn_exp2f(v[1]);
      t2 += __builtin_amdgcn_exp2f(v[2]);
      t3 += __builtin_amdgcn_exp2f(v[3]);
    }
  float tot = (t0 + t1) + (t2 + t3);

  // pos: only diagonal blocks / diagonal waves / diagonal frags contribute.
  float pos = 0.f;
  if (p0 == q0 && wr == wc) {
    const int col = lane & 15;
    const int rowb = (lane >> 4) * 4;
#pragma unroll
    for (int mi = 0; mi < 4; ++mi) {
#pragma unroll
      for (int r = 0; r < 4; ++r)
        if (rowb + r == col) pos += __builtin_amdgcn_exp2f(acc[mi][mi][r]);
    }
  }

  // wave reduce (64 lanes)
#pragma unroll
  for (int off = 32; off > 0; off >>= 1) {
    tot += __shfl_down(tot, off);
    pos += __shfl_down(pos, off);
  }
  __shared__ float sb[8];
  if (lane == 0) { sb[wid * 2] = pos; sb[wid * 2 + 1] = tot; }
  __syncthreads();
  if (threadIdx.x == 0) {
    const float pp = sb[0] + sb[2] + sb[4] + sb[6];
    const float tt = sb[1] + sb[3] + sb[5] + sb[7];
    const int bid = (n * 32 + blockIdx.y) * 32 + blockIdx.x;
    partials[bid * 2] = pp;
    partials[bid * 2 + 1] = tt;
  }
}

// Kernel 3: deterministic final reduction (1024 partials per n) + loss.
__global__ void __launch_bounds__(1024) finalize(
    const float* __restrict__ partials, float* __restrict__ out) {
  const int tid = threadIdx.x;
  const int lane = tid & 63, wid = tid >> 6;
  __shared__ float sp[16], st[16];
  float loss = 0.f;
  for (int n = 0; n < N_; ++n) {
    float p = partials[(n * 1024 + tid) * 2];
    float t = partials[(n * 1024 + tid) * 2 + 1];
#pragma unroll
    for (int off = 32; off > 0; off >>= 1) {
      p += __shfl_down(p, off);
      t += __shfl_down(t, off);
    }
    if (lane == 0) { sp[wid] = p; st[wid] = t; }
    __syncthreads();
    if (tid == 0) {
      float pp = 0.f, tt = 0.f;
#pragma unroll
      for (int w = 0; w < 16; ++w) { pp += sp[w]; tt += st[w]; }
      loss += -logf(pp / (tt + 1e-6f));
    }
    __syncthreads();
  }
  if (tid == 0) out[0] = loss * (1.0f / N_);
}

extern "C" void kernel_launch(void* const* d_in, const int* in_sizes, int n_in,
                              void* d_out, int out_size, void* d_ws, size_t ws_size,
                              hipStream_t stream) {
  const float* rgb = (const float*)d_in[0];
  const float* ir = (const float*)d_in[1];
  float* out = (float*)d_out;

  unsigned short* rgbnT = (unsigned short*)d_ws;              // 4 MB
  unsigned short* irnT = rgbnT + (size_t)N_ * P_ * C_;        // 4 MB
  float* partials = (float*)(irnT + (size_t)N_ * P_ * C_);    // 64 KB

  dim3 g1(N_ * P_ / 256, 2);
  norm_transpose<<<g1, 256, 0, stream>>>(rgb, ir, rgbnT, irnT);

  dim3 g2(P_ / TILE, P_ / TILE, N_);
  gemm_exp_reduce<<<g2, 256, 0, stream>>>(rgbnT, irnT, partials);

  finalize<<<1, 1024, 0, stream>>>(partials, out);
}

// Round 3
// 52.299 us; speedup vs baseline: 1.6273x; 1.6164x over previous
//
#include <hip/hip_runtime.h>

#define N_ 8
#define C_ 64
#define P_ 4096

typedef float f32x4 __attribute__((ext_vector_type(4)));
typedef short bf16x8 __attribute__((ext_vector_type(8)));

__device__ __forceinline__ unsigned short f2bf(float f) {
  unsigned int u = __builtin_bit_cast(unsigned int, f);
  u = (u + 0x7fffu + ((u >> 16) & 1u)) >> 16;  // RNE
  return (unsigned short)u;
}

// Kernel 1: L2-normalize along C, write bf16 transposed to [N][P][C].
// rgb side is pre-scaled by 10*log2(e) so the GEMM epilogue is exp2(acc).
__global__ void __launch_bounds__(256) norm_transpose(
    const float* __restrict__ rgb, const float* __restrict__ ir,
    unsigned short* __restrict__ rgbnT, unsigned short* __restrict__ irnT) {
  const int idx = blockIdx.x * 256 + threadIdx.x;  // over N*P
  const int n = idx >> 12;
  const int p = idx & (P_ - 1);
  const float* src = (blockIdx.y == 0) ? rgb : ir;
  unsigned short* dst = (blockIdx.y == 0) ? rgbnT : irnT;
  const float SC = 14.4269504088896340736f;  // 10*log2(e)
  const float* col = src + (size_t)n * C_ * P_ + p;
  float v[C_];
  float ss = 0.f;
#pragma unroll
  for (int c = 0; c < C_; ++c) {
    v[c] = col[(size_t)c * P_];
    ss += v[c] * v[c];
  }
  float inv = 1.0f / fmaxf(sqrtf(ss), 1e-12f);
  if (blockIdx.y == 0) inv *= SC;
  unsigned short* o = dst + ((size_t)n * P_ + p) * C_;
#pragma unroll
  for (int g = 0; g < 8; ++g) {
    bf16x8 pack;
#pragma unroll
    for (int j = 0; j < 8; ++j) pack[j] = (short)f2bf(v[g * 8 + j] * inv);
    *reinterpret_cast<bf16x8*>(o + g * 8) = pack;
  }
}

// Kernel 2: block = 128p x 1024q stripe. 4 waves (2x2); each wave holds its
// 64x64 A block in registers and loops over 8 q-subtiles of 64 with
// single-stage B prefetch. Fused exp2 + {diag, tot} partials.
#define LOADB(dstv, qrow)                                                  \
  _Pragma("unroll") for (int ks = 0; ks < 2; ++ks)                         \
  _Pragma("unroll") for (int ni = 0; ni < 4; ++ni)                         \
      dstv[ks][ni] = *reinterpret_cast<const bf16x8*>(                     \
          B + (size_t)((qrow) + ni * 16 + r16) * C_ + ks * 32 + kofs);

__global__ void __launch_bounds__(256) gemm_exp_reduce(
    const unsigned short* __restrict__ aT, const unsigned short* __restrict__ bT,
    float* __restrict__ partials) {
  const int n = blockIdx.z;
  const int p0 = blockIdx.x * 128;
  const int qc = blockIdx.y * 1024;
  const int lane = threadIdx.x & 63;
  const int wid = threadIdx.x >> 6;
  const int wr = wid >> 1, wc = wid & 1;
  const int pbase = p0 + wr * 64;
  const int qwb = qc + wc * 512;  // this wave's q stripe: 8 subtiles of 64
  const unsigned short* A = aT + (size_t)n * P_ * C_;  // [P][C]
  const unsigned short* B = bT + (size_t)n * P_ * C_;  // [P][C]
  const int r16 = lane & 15;
  const int kofs = (lane >> 4) * 8;

  // A fragments: resident in registers for the whole kernel (32 VGPR).
  bf16x8 af[2][4];
#pragma unroll
  for (int ks = 0; ks < 2; ++ks)
#pragma unroll
    for (int mi = 0; mi < 4; ++mi)
      af[ks][mi] = *reinterpret_cast<const bf16x8*>(
          A + (size_t)(pbase + mi * 16 + r16) * C_ + ks * 32 + kofs);

  float t0 = 0.f, t1 = 0.f, t2 = 0.f, t3 = 0.f, pos = 0.f;
  const int col = lane & 15;
  const int rowb = (lane >> 4) * 4;

  bf16x8 bcur[2][4];
  LOADB(bcur, qwb)

#pragma unroll 1
  for (int it = 0; it < 8; ++it) {
    const int qb = qwb + it * 64;
    bf16x8 bnxt[2][4];
    if (it < 7) { LOADB(bnxt, qb + 64) }

    f32x4 acc[4][4];
#pragma unroll
    for (int i = 0; i < 4; ++i)
#pragma unroll
      for (int j = 0; j < 4; ++j) acc[i][j] = (f32x4)(0.f);

#pragma unroll
    for (int ks = 0; ks < 2; ++ks)
#pragma unroll
      for (int mi = 0; mi < 4; ++mi)
#pragma unroll
        for (int ni = 0; ni < 4; ++ni)
          acc[mi][ni] = __builtin_amdgcn_mfma_f32_16x16x32_bf16(
              af[ks][mi], bcur[ks][ni], acc[mi][ni], 0, 0, 0);

    // Epilogue: logit = exp2(acc); 4 independent accumulators.
#pragma unroll
    for (int mi = 0; mi < 4; ++mi)
#pragma unroll
      for (int ni = 0; ni < 4; ++ni) {
        const f32x4 v = acc[mi][ni];
        t0 += __builtin_amdgcn_exp2f(v[0]);
        t1 += __builtin_amdgcn_exp2f(v[1]);
        t2 += __builtin_amdgcn_exp2f(v[2]);
        t3 += __builtin_amdgcn_exp2f(v[3]);
      }
    if (pbase == qb) {  // diagonal subtile: mi==ni frags, rowb+r==col elems
#pragma unroll
      for (int mi = 0; mi < 4; ++mi)
#pragma unroll
        for (int r = 0; r < 4; ++r)
          if (rowb + r == col) pos += __builtin_amdgcn_exp2f(acc[mi][mi][r]);
    }

#pragma unroll
    for (int ks = 0; ks < 2; ++ks)
#pragma unroll
      for (int ni = 0; ni < 4; ++ni) bcur[ks][ni] = bnxt[ks][ni];
  }

  float tot = (t0 + t1) + (t2 + t3);
#pragma unroll
  for (int off = 32; off > 0; off >>= 1) {
    tot += __shfl_down(tot, off);
    pos += __shfl_down(pos, off);
  }
  __shared__ float sb[8];
  if (lane == 0) { sb[wid * 2] = pos; sb[wid * 2 + 1] = tot; }
  __syncthreads();
  if (threadIdx.x == 0) {
    const float pp = sb[0] + sb[2] + sb[4] + sb[6];
    const float tt = sb[1] + sb[3] + sb[5] + sb[7];
    const int bid = (n * 4 + blockIdx.y) * 32 + blockIdx.x;
    partials[bid * 2] = pp;
    partials[bid * 2 + 1] = tt;
  }
}

// Kernel 3: reduce 128 partial pairs per n, compute loss. One pass.
__global__ void __launch_bounds__(1024) finalize(
    const float* __restrict__ partials, float* __restrict__ out) {
  const int tid = threadIdx.x;
  const int lane = tid & 63, wid = tid >> 6;  // 16 waves; 2 waves per n
  __shared__ float sp[16], st[16], sl[8];
  const int n = tid >> 7;
  const int i = tid & 127;
  float p = partials[(n * 128 + i) * 2];
  float t = partials[(n * 128 + i) * 2 + 1];
#pragma unroll
  for (int off = 32; off > 0; off >>= 1) {
    p += __shfl_down(p, off);
    t += __shfl_down(t, off);
  }
  if (lane == 0) { sp[wid] = p; st[wid] = t; }
  __syncthreads();
  if (tid < 8) {
    const float pp = sp[2 * tid] + sp[2 * tid + 1];
    const float tt = st[2 * tid] + st[2 * tid + 1];
    sl[tid] = -logf(pp / (tt + 1e-6f));
  }
  __syncthreads();
  if (tid == 0) {
    float loss = 0.f;
#pragma unroll
    for (int k = 0; k < 8; ++k) loss += sl[k];
    out[0] = loss * (1.0f / N_);
  }
}

extern "C" void kernel_launch(void* const* d_in, const int* in_sizes, int n_in,
                              void* d_out, int out_size, void* d_ws, size_t ws_size,
                              hipStream_t stream) {
  const float* rgb = (const float*)d_in[0];
  const float* ir = (const float*)d_in[1];
  float* out = (float*)d_out;

  unsigned short* rgbnT = (unsigned short*)d_ws;              // 4 MB
  unsigned short* irnT = rgbnT + (size_t)N_ * P_ * C_;        // 4 MB
  float* partials = (float*)(irnT + (size_t)N_ * P_ * C_);    // 8 KB

  dim3 g1(N_ * P_ / 256, 2);
  norm_transpose<<<g1, 256, 0, stream>>>(rgb, ir, rgbnT, irnT);

  dim3 g2(P_ / 128, P_ / 1024, N_);
  gemm_exp_reduce<<<g2, 256, 0, stream>>>(rgbnT, irnT, partials);

  finalize<<<1, 1024, 0, stream>>>(partials, out);
}